// Round 1
// baseline (14685.374 us; speedup 1.0000x reference)
//
#include <hip/hip_runtime.h>
#include <hip/hip_bf16.h>
#include <math.h>

// ---------------- problem constants ----------------
#define T_STEPS 256
#define BATCH   16
#define FDIM    256
#define NB      64
#define NPB     64
#define NTOT    4096
#define NNZ     512
#define SUBSTEPS 5
#define NWG     64

// persistent-kernel LDS budget
#define MAXB 12            // weight blocks resident in LDS per row (8 KB each, bf16)
#define MAXC 20            // staged s col-blocks per substep (2 KB each)
#define DYN_BYTES (MAXB*8192 + MAXC*2048)   // 139264 B < 160 KiB

// workspace layout (bytes)
#define SYNC_OFF  0        // 2 KB of counters
#define SBF_OFF   4096     // 2 x (16*4096) bf16 = 256 KB double buffer
#define WFRAG_OFF 524288   // 512 * 8 KB bf16 fragment-linear weights = 4 MB

typedef float f32x4 __attribute__((ext_vector_type(4)));
typedef short bf16x8 __attribute__((ext_vector_type(8)));

__device__ __forceinline__ unsigned short f2bf(float x) {
  unsigned u = __float_as_uint(x);
  u += 0x7fffu + ((u >> 16) & 1u);
  return (unsigned short)(u >> 16);
}

// ---------------- init: zero sync counters ----------------
__global__ void k_init(unsigned* __restrict__ sync) {
  sync[threadIdx.x] = 0u;
  sync[threadIdx.x + 256] = 0u;
}

// ---------------- drive GEMM: drive[m][n] = gain[n]*sum_f ext[m][f]*win[n][f] + bias[n]
// m = t*16+b over 4096, n over 4096, K = 256. 64x64 tiles, f32.
__global__ __launch_bounds__(256) void k_gemm(const float* __restrict__ ext,
                                              const float* __restrict__ win,
                                              const float* __restrict__ gain,
                                              const float* __restrict__ bias,
                                              float* __restrict__ drive) {
  __shared__ float As[64][68];
  __shared__ float WsT[64][68];   // transposed: [k][n]
  const int tid = threadIdx.x;
  const int m0 = blockIdx.y << 6;
  const int n0 = blockIdx.x << 6;
  const int tx = tid & 15, ty = tid >> 4;
  float acc[4][4] = {};
  for (int kc = 0; kc < FDIM; kc += 64) {
    __syncthreads();
#pragma unroll
    for (int rep = 0; rep < 4; ++rep) {
      int idx = tid + rep * 256;
      int row = idx >> 4;
      int c4 = (idx & 15) << 2;
      float4 av = *(const float4*)&ext[(size_t)(m0 + row) * FDIM + kc + c4];
      *(float4*)&As[row][c4] = av;
      float4 wv4 = *(const float4*)&win[(size_t)(n0 + row) * FDIM + kc + c4];
      WsT[c4 + 0][row] = wv4.x; WsT[c4 + 1][row] = wv4.y;
      WsT[c4 + 2][row] = wv4.z; WsT[c4 + 3][row] = wv4.w;
    }
    __syncthreads();
#pragma unroll 4
    for (int k = 0; k < 64; ++k) {
      float a_[4], w_[4];
#pragma unroll
      for (int i = 0; i < 4; ++i) a_[i] = As[ty * 4 + i][k];
#pragma unroll
      for (int j = 0; j < 4; ++j) w_[j] = WsT[k][tx * 4 + j];
#pragma unroll
      for (int i = 0; i < 4; ++i)
#pragma unroll
        for (int j = 0; j < 4; ++j) acc[i][j] = fmaf(a_[i], w_[j], acc[i][j]);
    }
  }
#pragma unroll
  for (int i = 0; i < 4; ++i) {
    int m = m0 + ty * 4 + i;
#pragma unroll
    for (int j = 0; j < 4; ++j) {
      int n = n0 + tx * 4 + j;
      drive[(size_t)m * NTOT + n] = gain[n] * acc[i][j] + bias[n];
    }
  }
}

// ---------------- weight prep: fragment-linear bf16 layout ----------------
// For slot sl, kk2 (K-half 0/1), wave-tile wt, lane l, elem e(0..7):
//   value = W[sl][ i = wt*16 + (l&15) ][ j = kk2*32 + (l>>4)*8 + e ]
// flat ushort index = (((sl*2 + kk2)*4 + wt)*64 + l)*8 + e   (16 B per lane, coalesced)
__global__ __launch_bounds__(256) void k_wprep(const float* __restrict__ wv,
                                               unsigned short* __restrict__ wfrag) {
  const int sl = blockIdx.x;
  const int kk2 = blockIdx.y;
  const int tid = threadIdx.x;
  const int l = tid & 63, wt = tid >> 6;
  const int c = l & 15, g = l >> 4;
  const int i = wt * 16 + c;
  __align__(16) unsigned short tmp[8];
#pragma unroll
  for (int e = 0; e < 8; ++e) {
    int j = kk2 * 32 + g * 8 + e;
    tmp[e] = f2bf(wv[((size_t)sl * 64 + i) * 64 + j]);
  }
  size_t off = (((size_t)(sl * 2 + kk2) * 4 + wt) * 64 + l) * 8;
  *(uint4*)(wfrag + off) = *(const uint4*)tmp;
}

// ---------------- two-level grid barrier (64 WGs, all co-resident) ----------------
__device__ __forceinline__ void gbar(unsigned* sync, int wg, unsigned target) {
  __syncthreads();                       // drain this WG's stores (vmcnt 0 before s_barrier)
  if (threadIdx.x == 0) {
    __threadfence();                     // release: writeback to agent-visible point
    unsigned* grp  = sync + ((wg & 7) << 5);   // 128 B apart
    unsigned* root = sync + (8 << 5);
    unsigned* gen  = sync + (9 << 5);
    unsigned old = __hip_atomic_fetch_add(grp, 1u, __ATOMIC_RELAXED, __HIP_MEMORY_SCOPE_AGENT);
    if (old == target * 8u - 1u) {
      unsigned o2 = __hip_atomic_fetch_add(root, 1u, __ATOMIC_RELAXED, __HIP_MEMORY_SCOPE_AGENT);
      if (o2 == target * 8u - 1u)
        __hip_atomic_store(gen, target, __ATOMIC_RELEASE, __HIP_MEMORY_SCOPE_AGENT);
    }
    while (__hip_atomic_load(gen, __ATOMIC_RELAXED, __HIP_MEMORY_SCOPE_AGENT) < target)
      __builtin_amdgcn_s_sleep(2);
    __threadfence();                     // acquire: invalidate caches for fresh reads
  }
  __syncthreads();
}

// ---------------- persistent recurrent kernel ----------------
// WG r owns row-block r (neurons r*64..r*64+63) x all 16 batches.
// Wave wt owns 16 neurons; lane: c=l&15 (batch for A / neuron-col for D), g=l>>4.
// D mapping (verified): batch b = g*4+q, neuron n = r*64 + wt*16 + c.
__global__ __launch_bounds__(256) void k_persist(const float* __restrict__ s0,
                                                 const int* __restrict__ rows_g,
                                                 const int* __restrict__ cols_g,
                                                 const unsigned short* __restrict__ wfrag,
                                                 unsigned short* __restrict__ sbf,
                                                 float* __restrict__ out,
                                                 unsigned* __restrict__ sync) {
  extern __shared__ char dynsm[];
  unsigned short* wlds = (unsigned short*)dynsm;        // MAXB * 8192 B
  char* sstage = dynsm + MAXB * 8192;                   // MAXC * 2048 B, XOR-swizzled
  __shared__ int sh_cols[64];
  __shared__ int sh_lt, sh_eq;

  const int r = blockIdx.x;
  const int tid = threadIdx.x;
  const int l = tid & 63, wt = tid >> 6;
  const int c = l & 15, g = l >> 4;
  const int n_own = r * 64 + wt * 16 + c;
  const float d_f = 0.81873077f;        // exp(-0.2) in f32, matches jnp.exp(float32(-0.2))
  const float omd = 1.0f - d_f;

  // ---- find this row's nnz range (parallel count over sorted rows[]) ----
  if (tid == 0) { sh_lt = 0; sh_eq = 0; }
  __syncthreads();
  {
    int lt = 0, eq = 0;
    for (int k = tid; k < NNZ; k += 256) {
      int rv = rows_g[k];
      lt += (rv < r); eq += (rv == r);
    }
    atomicAdd(&sh_lt, lt); atomicAdd(&sh_eq, eq);
  }
  __syncthreads();
  const int start = sh_lt;
  const int cnt = min(sh_eq, 64);
  if (tid < cnt) sh_cols[tid] = cols_g[start + tid];

  // ---- LDS-resident weight fragments (first MAXB blocks, contiguous copy) ----
  const int nb_l = min(cnt, MAXB);
  for (int off = tid * 8; off < nb_l * 4096; off += 256 * 8)
    *(uint4*)(wlds + off) = *(const uint4*)(wfrag + (size_t)start * 4096 + off);

  // ---- own state in f32 registers; publish bf16 s to buffer 0 ----
  float sreg[4];
#pragma unroll
  for (int q = 0; q < 4; ++q) {
    sreg[q] = s0[(size_t)(g * 4 + q) * NTOT + n_own];
    sbf[(size_t)(g * 4 + q) * NTOT + n_own] = f2bf(sreg[q]);
  }
  float drv[4];
#pragma unroll
  for (int q = 0; q < 4; ++q) drv[q] = out[(size_t)(g * 4 + q) * NTOT + n_own]; // drive[t=0]

  unsigned target = 1;
  gbar(sync, r, target++);   // barrier 0: s_bf[0] + weights globally ready

  int buf = 0;
  for (int t = 0; t < T_STEPS; ++t) {
    float drvc[4];
#pragma unroll
    for (int q = 0; q < 4; ++q) drvc[q] = drv[q];

    for (int ss = 0; ss < SUBSTEPS; ++ss) {
      const unsigned short* sb_cur = sbf + (size_t)buf * (BATCH * NTOT);
      unsigned short* sb_nxt = sbf + (size_t)(buf ^ 1) * (BATCH * NTOT);

      // ---- cooperative stage of needed s col-blocks into swizzled LDS ----
      const int nc_l = min(cnt, MAXC);
      for (int off = tid * 16; off < nc_l * 2048; off += 256 * 16) {
        int blk = off >> 11;
        int r2 = off & 2047;
        int b = r2 >> 7;
        int jl = r2 & 127;                       // byte-within-row, 16B granular
        const char* src = (const char*)sb_cur + (size_t)b * 8192 + (size_t)sh_cols[blk] * 128 + jl;
        char* dst = sstage + blk * 2048 + (((b * 128 + jl) ^ ((b & 7) << 4)));
        *(uint4*)dst = *(const uint4*)src;
      }
      __syncthreads();

      // ---- block-sparse matvec via MFMA: acc[q] = y[b=g*4+q][n_own] ----
      f32x4 acc = {0.f, 0.f, 0.f, 0.f};
      for (int k = 0; k < cnt; ++k) {
        bf16x8 a0, a1, b0, b1;
        if (k < MAXC) {
          const char* ab = sstage + k * 2048;
          int raw0 = (c * 128 + g * 16) ^ ((c & 7) << 4);
          int raw1 = (c * 128 + 64 + g * 16) ^ ((c & 7) << 4);
          a0 = *(const bf16x8*)(ab + raw0);
          a1 = *(const bf16x8*)(ab + raw1);
        } else {   // rare overflow: direct global read
          const char* ab = (const char*)sb_cur + (size_t)c * 8192 + (size_t)sh_cols[k] * 128 + g * 16;
          a0 = *(const bf16x8*)(ab);
          a1 = *(const bf16x8*)(ab + 64);
        }
        if (k < MAXB) {
          const char* bb = (const char*)wlds + (size_t)k * 8192 + (size_t)(wt * 64 + l) * 16;
          b0 = *(const bf16x8*)(bb);
          b1 = *(const bf16x8*)(bb + 4096);
        } else {   // overflow blocks: stream from L2/L3 (fragment-linear, coalesced)
          const char* bb = (const char*)wfrag + (size_t)(start + k) * 8192 + (size_t)(wt * 64 + l) * 16;
          b0 = *(const bf16x8*)(bb);
          b1 = *(const bf16x8*)(bb + 4096);
        }
        acc = __builtin_amdgcn_mfma_f32_16x16x32_bf16(a0, b0, acc, 0, 0, 0);
        acc = __builtin_amdgcn_mfma_f32_16x16x32_bf16(a1, b1, acc, 0, 0, 0);
      }

      // ---- state update (f32 master), publish bf16 for next substep ----
#pragma unroll
      for (int q = 0; q < 4; ++q) {
        float pre = acc[q] + drvc[q];
        sreg[q] = d_f * sreg[q] + omd * tanhf(pre);
        sb_nxt[(size_t)(g * 4 + q) * NTOT + n_own] = f2bf(sreg[q]);
      }
      buf ^= 1;
      gbar(sync, r, target++);
    }

    // traj[t] = s (f32), overwriting drive[t] (already consumed)
#pragma unroll
    for (int q = 0; q < 4; ++q)
      out[((size_t)t * BATCH + (g * 4 + q)) * NTOT + n_own] = sreg[q];
    // prefetch next step's drive (overlaps next substep staging)
    if (t + 1 < T_STEPS) {
#pragma unroll
      for (int q = 0; q < 4; ++q)
        drv[q] = out[((size_t)(t + 1) * BATCH + (g * 4 + q)) * NTOT + n_own];
    }
  }
}

// ---------------- launcher ----------------
extern "C" void kernel_launch(void* const* d_in, const int* in_sizes, int n_in,
                              void* d_out, int out_size, void* d_ws, size_t ws_size,
                              hipStream_t stream) {
  const float* ext  = (const float*)d_in[0];
  const float* win  = (const float*)d_in[1];
  const float* gain = (const float*)d_in[2];
  const float* bias = (const float*)d_in[3];
  const float* wv   = (const float*)d_in[4];
  const float* s0   = (const float*)d_in[5];
  // d_in[6] = state_e, d_in[7] = state_a : dead in the reference output, skipped
  const int* rows = (const int*)d_in[8];
  const int* cols = (const int*)d_in[9];
  float* out = (float*)d_out;

  char* ws = (char*)d_ws;
  unsigned* sync = (unsigned*)(ws + SYNC_OFF);
  unsigned short* sbf = (unsigned short*)(ws + SBF_OFF);
  unsigned short* wfrag = (unsigned short*)(ws + WFRAG_OFF);

  hipFuncSetAttribute((const void*)k_persist,
                      hipFuncAttributeMaxDynamicSharedMemorySize, DYN_BYTES);

  k_init<<<1, 256, 0, stream>>>(sync);
  k_gemm<<<dim3(64, 64), 256, 0, stream>>>(ext, win, gain, bias, out);
  k_wprep<<<dim3(512, 2), 256, 0, stream>>>(wv, wfrag);
  k_persist<<<NWG, 256, DYN_BYTES, stream>>>(s0, rows, cols, wfrag, sbf, out, sync);
}

// Round 2
// 7027.667 us; speedup vs baseline: 2.0897x; 2.0897x over previous
//
#include <hip/hip_runtime.h>
#include <hip/hip_bf16.h>
#include <math.h>

// ---------------- problem constants ----------------
#define T_STEPS 256
#define BATCH   16
#define FDIM    256
#define NTOT    4096
#define NNZ     512
#define NWG     64

#define MAXK    20          // blocks handled via reg-weights + LDS staging
#define STG_MAX 10          // staging sweeps: MAXK*2048 / (256*16)
#define DEPTH   4           // s exchange buffers

// workspace layout (bytes)
#define SYNC_OFF  0                         // 64 flags
#define SBF_OFF   4096                      // DEPTH * 128 KB
#define SBUF_BYTES (64*BATCH*64*2)          // 131072 per buffer (block-major)
#define WFRAG_OFF (4096 + DEPTH*SBUF_BYTES) // 528384; 4 MB of bf16 fragments

typedef float f32x4 __attribute__((ext_vector_type(4)));
typedef short bf16x8 __attribute__((ext_vector_type(8)));

__device__ __forceinline__ unsigned short f2bf(float x) {
  unsigned u = __float_as_uint(x);
  u += 0x7fffu + ((u >> 16) & 1u);
  return (unsigned short)(u >> 16);
}

// ---- coherence-point (L2-bypassing) ops: cross-XCD visible without fences ----
__device__ __forceinline__ bf16x8 sc_load16(const void* p) {
  bf16x8 r;
  asm volatile("global_load_dwordx4 %0, %1, off sc0 sc1"
               : "=&v"(r) : "v"(p) : "memory");
  return r;
}
__device__ __forceinline__ bf16x8 sc_load16_wait(const void* p) {
  bf16x8 r;
  asm volatile("global_load_dwordx4 %0, %1, off sc0 sc1\n\ts_waitcnt vmcnt(0)"
               : "=&v"(r) : "v"(p) : "memory");
  return r;
}
__device__ __forceinline__ void sc_store_short(void* p, unsigned v) {
  asm volatile("global_store_short %0, %1, off sc0 sc1"
               :: "v"(p), "v"(v) : "memory");
}

// ---------------- init: zero sync flags ----------------
__global__ void k_init(unsigned* __restrict__ sync) {
  sync[threadIdx.x] = 0u;
}

// ---------------- drive GEMM: drive[m][n] = gain[n]*sum_f ext[m][f]*win[n][f] + bias[n]
__global__ __launch_bounds__(256) void k_gemm(const float* __restrict__ ext,
                                              const float* __restrict__ win,
                                              const float* __restrict__ gain,
                                              const float* __restrict__ bias,
                                              float* __restrict__ drive) {
  __shared__ float As[64][68];
  __shared__ float WsT[64][68];
  const int tid = threadIdx.x;
  const int m0 = blockIdx.y << 6;
  const int n0 = blockIdx.x << 6;
  const int tx = tid & 15, ty = tid >> 4;
  float acc[4][4] = {};
  for (int kc = 0; kc < FDIM; kc += 64) {
    __syncthreads();
#pragma unroll
    for (int rep = 0; rep < 4; ++rep) {
      int idx = tid + rep * 256;
      int row = idx >> 4;
      int c4 = (idx & 15) << 2;
      float4 av = *(const float4*)&ext[(size_t)(m0 + row) * FDIM + kc + c4];
      *(float4*)&As[row][c4] = av;
      float4 wv4 = *(const float4*)&win[(size_t)(n0 + row) * FDIM + kc + c4];
      WsT[c4 + 0][row] = wv4.x; WsT[c4 + 1][row] = wv4.y;
      WsT[c4 + 2][row] = wv4.z; WsT[c4 + 3][row] = wv4.w;
    }
    __syncthreads();
#pragma unroll 4
    for (int k = 0; k < 64; ++k) {
      float a_[4], w_[4];
#pragma unroll
      for (int i = 0; i < 4; ++i) a_[i] = As[ty * 4 + i][k];
#pragma unroll
      for (int j = 0; j < 4; ++j) w_[j] = WsT[k][tx * 4 + j];
#pragma unroll
      for (int i = 0; i < 4; ++i)
#pragma unroll
        for (int j = 0; j < 4; ++j) acc[i][j] = fmaf(a_[i], w_[j], acc[i][j]);
    }
  }
#pragma unroll
  for (int i = 0; i < 4; ++i) {
    int m = m0 + ty * 4 + i;
#pragma unroll
    for (int j = 0; j < 4; ++j) {
      int n = n0 + tx * 4 + j;
      drive[(size_t)m * NTOT + n] = gain[n] * acc[i][j] + bias[n];
    }
  }
}

// ---------------- weight prep: fragment-linear bf16 (B-operand) ----------------
__global__ __launch_bounds__(256) void k_wprep(const float* __restrict__ wv,
                                               unsigned short* __restrict__ wfrag) {
  const int sl = blockIdx.x;
  const int kk2 = blockIdx.y;
  const int tid = threadIdx.x;
  const int l = tid & 63, wt = tid >> 6;
  const int c = l & 15, g = l >> 4;
  const int i = wt * 16 + c;
  __align__(16) unsigned short tmp[8];
#pragma unroll
  for (int e = 0; e < 8; ++e) {
    int j = kk2 * 32 + g * 8 + e;
    tmp[e] = f2bf(wv[((size_t)sl * 64 + i) * 64 + j]);
  }
  size_t off = (((size_t)(sl * 2 + kk2) * 4 + wt) * 64 + l) * 8;
  *(uint4*)(wfrag + off) = *(const uint4*)tmp;
}

// ---------------- persistent recurrent kernel (point-to-point sync) ----------------
__global__ __launch_bounds__(256, 1) void k_persist(const float* __restrict__ s0,
                                                    const int* __restrict__ rows_g,
                                                    const int* __restrict__ cols_g,
                                                    const unsigned short* __restrict__ wfrag,
                                                    char* __restrict__ sbuf,
                                                    float* __restrict__ out,
                                                    unsigned* __restrict__ flags) {
  __shared__ char sstage[MAXK * 2048];   // XOR-swizzled staged s col-blocks
  __shared__ int sh_cols[64];
  __shared__ int sh_lt, sh_eq;
  __shared__ unsigned m_pl, m_ph, m_cl, m_ch;

  const int r = blockIdx.x;
  const int tid = threadIdx.x;
  const int l = tid & 63, wt = tid >> 6;
  const int c = l & 15, g = l >> 4;
  const int n_own = r * 64 + wt * 16 + c;
  const float d_f = 0.81873077f;   // exp(-0.2f)
  const float omd = 1.0f - d_f;

  // ---- scan rows/cols: nnz range + producer/consumer masks ----
  if (tid == 0) { sh_lt = 0; sh_eq = 0; m_pl = 0; m_ph = 0; m_cl = 0; m_ch = 0; }
  __syncthreads();
  {
    int lt = 0, eq = 0;
    for (int k = tid; k < NNZ; k += 256) {
      int rv = rows_g[k], cv = cols_g[k];
      lt += (rv < r); eq += (rv == r);
      if (rv == r) { if (cv < 32) atomicOr(&m_pl, 1u << cv); else atomicOr(&m_ph, 1u << (cv - 32)); }
      if (cv == r) { if (rv < 32) atomicOr(&m_cl, 1u << rv); else atomicOr(&m_ch, 1u << (rv - 32)); }
    }
    atomicAdd(&sh_lt, lt); atomicAdd(&sh_eq, eq);
  }
  __syncthreads();
  const int start = sh_lt;
  const int cnt = min(sh_eq, 64);
  if (tid < cnt) sh_cols[tid] = cols_g[start + tid];
  __syncthreads();
  const unsigned long long pmask = ((unsigned long long)m_ph << 32) | m_pl;
  const unsigned long long cmask = ((unsigned long long)m_ch << 32) | m_cl;

  // ---- weights -> registers (guarded static unroll; B-fragment layout) ----
  const char* wfb = (const char*)wfrag;
  bf16x8 wb0[MAXK], wb1[MAXK];
#pragma unroll
  for (int k = 0; k < MAXK; ++k) {
    if (k < cnt) {
      const char* bb = wfb + (size_t)(start + k) * 8192 + (size_t)(wt * 64 + l) * 16;
      wb0[k] = *(const bf16x8*)(bb);
      wb1[k] = *(const bf16x8*)(bb + 4096);
    }
  }
  const int cnt2 = min(cnt, MAXK);

  // ---- init state; publish s^(0) to buffer 0 ----
  float sreg[4];
#pragma unroll
  for (int q = 0; q < 4; ++q) sreg[q] = s0[(size_t)(g * 4 + q) * NTOT + n_own];
  {
    char* me = sbuf + (size_t)r * 2048;
#pragma unroll
    for (int q = 0; q < 4; ++q)
      sc_store_short(me + (g * 4 + q) * 128 + (wt * 16 + c) * 2, (unsigned)f2bf(sreg[q]));
  }
  float drv[4];
#pragma unroll
  for (int q = 0; q < 4; ++q) drv[q] = out[(size_t)(g * 4 + q) * NTOT + n_own];

  asm volatile("s_waitcnt vmcnt(0)" ::: "memory");
  __syncthreads();
  if (tid == 0)
    __hip_atomic_store(&flags[r], 1u, __ATOMIC_RELAXED, __HIP_MEMORY_SCOPE_AGENT);

  const int raw0 = (c * 128 + g * 16) ^ ((c & 7) << 4);
  const int raw1 = (c * 128 + 64 + g * 16) ^ ((c & 7) << 4);
  const int nbytes = min(cnt, MAXK) * 2048;

  for (int t = 0; t < T_STEPS; ++t) {
    for (int ss = 0; ss < 5; ++ss) {
      const int i = t * 5 + ss + 1;
      // ---- wait: producers published s^(i-1); consumers done with s^(i-4) ----
      if (tid < 64) {
        unsigned need_p = (unsigned)i;
        int nc = i - (DEPTH - 2);
        unsigned need_c = nc > 0 ? (unsigned)nc : 0u;
        int guard = 0;
        for (;;) {
          unsigned f = __hip_atomic_load(&flags[l], __ATOMIC_RELAXED, __HIP_MEMORY_SCOPE_AGENT);
          unsigned long long bp = __ballot(f >= need_p);
          unsigned long long bc = __ballot(f >= need_c);
          if (((bp & pmask) == pmask) && ((bc & cmask) == cmask)) break;
          if (++guard > (1 << 22)) break;   // bailout: fail visibly, don't hang
          __builtin_amdgcn_s_sleep(2);
        }
      }
      __syncthreads();

      // ---- stage s col-blocks into swizzled LDS (pipelined sc loads) ----
      const char* sb_prev = sbuf + (size_t)((i - 1) & (DEPTH - 1)) * SBUF_BYTES;
      bf16x8 stg[STG_MAX];
#pragma unroll
      for (int sw = 0; sw < STG_MAX; ++sw) {
        int off = tid * 16 + sw * 4096;
        if (off < nbytes) {
          int blk = off >> 11;
          int r2 = off & 2047;
          stg[sw] = sc_load16(sb_prev + (size_t)sh_cols[blk] * 2048 + r2);
        }
      }
      asm volatile("s_waitcnt vmcnt(0)" ::: "memory");
      __builtin_amdgcn_sched_barrier(0);
#pragma unroll
      for (int sw = 0; sw < STG_MAX; ++sw) {
        int off = tid * 16 + sw * 4096;
        if (off < nbytes) {
          int blk = off >> 11;
          int r2 = off & 2047;
          int b = r2 >> 7;
          int jl = r2 & 127;
          *(bf16x8*)(sstage + blk * 2048 + ((b * 128 + jl) ^ ((b & 7) << 4))) = stg[sw];
        }
      }
      __syncthreads();

      // ---- block-sparse matvec: reg weights x LDS s-fragments ----
      f32x4 acc = {0.f, 0.f, 0.f, 0.f};
#pragma unroll
      for (int k = 0; k < MAXK; ++k) {
        if (k < cnt2) {
          const char* ab = sstage + k * 2048;
          bf16x8 a0 = *(const bf16x8*)(ab + raw0);
          bf16x8 a1 = *(const bf16x8*)(ab + raw1);
          acc = __builtin_amdgcn_mfma_f32_16x16x32_bf16(a0, wb0[k], acc, 0, 0, 0);
          acc = __builtin_amdgcn_mfma_f32_16x16x32_bf16(a1, wb1[k], acc, 0, 0, 0);
        }
      }
      for (int k = MAXK; k < cnt; ++k) {   // rare overflow: direct coherent reads
        const char* bb = wfb + (size_t)(start + k) * 8192 + (size_t)(wt * 64 + l) * 16;
        bf16x8 b0 = *(const bf16x8*)(bb);
        bf16x8 b1 = *(const bf16x8*)(bb + 4096);
        const char* ab = sb_prev + (size_t)sh_cols[k] * 2048 + c * 128 + g * 16;
        bf16x8 a0 = sc_load16_wait(ab);
        bf16x8 a1 = sc_load16_wait(ab + 64);
        acc = __builtin_amdgcn_mfma_f32_16x16x32_bf16(a0, b0, acc, 0, 0, 0);
        acc = __builtin_amdgcn_mfma_f32_16x16x32_bf16(a1, b1, acc, 0, 0, 0);
      }

      // ---- state update; publish s^(i) ----
      char* me = sbuf + (size_t)(i & (DEPTH - 1)) * SBUF_BYTES + (size_t)r * 2048;
#pragma unroll
      for (int q = 0; q < 4; ++q) {
        float pre = acc[q] + drv[q];
        sreg[q] = d_f * sreg[q] + omd * tanhf(pre);
        sc_store_short(me + (g * 4 + q) * 128 + (wt * 16 + c) * 2, (unsigned)f2bf(sreg[q]));
      }
      asm volatile("s_waitcnt vmcnt(0)" ::: "memory");
      __syncthreads();
      if (tid == 0)
        __hip_atomic_store(&flags[r], (unsigned)(i + 1), __ATOMIC_RELAXED, __HIP_MEMORY_SCOPE_AGENT);
    }

    // traj[t] = s (private, cached path); prefetch next drive
#pragma unroll
    for (int q = 0; q < 4; ++q)
      out[((size_t)t * BATCH + (g * 4 + q)) * NTOT + n_own] = sreg[q];
    if (t + 1 < T_STEPS) {
#pragma unroll
      for (int q = 0; q < 4; ++q)
        drv[q] = out[((size_t)(t + 1) * BATCH + (g * 4 + q)) * NTOT + n_own];
    }
  }
}

// ---------------- launcher ----------------
extern "C" void kernel_launch(void* const* d_in, const int* in_sizes, int n_in,
                              void* d_out, int out_size, void* d_ws, size_t ws_size,
                              hipStream_t stream) {
  const float* ext  = (const float*)d_in[0];
  const float* win  = (const float*)d_in[1];
  const float* gain = (const float*)d_in[2];
  const float* bias = (const float*)d_in[3];
  const float* wv   = (const float*)d_in[4];
  const float* s0   = (const float*)d_in[5];
  const int* rows = (const int*)d_in[8];
  const int* cols = (const int*)d_in[9];
  float* out = (float*)d_out;

  char* ws = (char*)d_ws;
  unsigned* sync = (unsigned*)(ws + SYNC_OFF);
  char* sbuf = ws + SBF_OFF;
  unsigned short* wfrag = (unsigned short*)(ws + WFRAG_OFF);

  k_init<<<1, 256, 0, stream>>>(sync);
  k_gemm<<<dim3(64, 64), 256, 0, stream>>>(ext, win, gain, bias, out);
  k_wprep<<<dim3(512, 2), 256, 0, stream>>>(wv, wfrag);
  k_persist<<<NWG, 256, 0, stream>>>(s0, rows, cols, wfrag, sbuf, out, sync);
}